// Round 16
// baseline (764.938 us; speedup 1.0000x reference)
//
#include <hip/hip_runtime.h>
#include <math.h>

#define SS 4096
#define EE 1024
#define HH 16
#define DD 64
#define RMAX 128
#define NCOL 128
#define NTR  8
#define NRED 8
#define NPROJ 192  // 3 m * 64 e-tiles(16e); W read exactly once, xT re-read 4x less
#define NBG 64     // bgA GEMV blocks in D2
#define NVS 16     // vsumh blocks in D2
#define NATT 256   // attention blocks in D2
#define REP 16     // instrumentation: d1 only

// ---------------------------------------------------------------------------
// ws float offsets. LESSONS: (r9/r10) no 4KB-strided ws reads; (r3) no BULK
// global atomics; (r5/r7) no software grid barriers; (r13) no shallow-flight
// staging loops; (r14) scalar W loads cap at 700 GB/s; (r15→16) every proj
// block re-reading all of xT = 384 MB L2 traffic — amortize with wider e-tiles.
//   meta   int[0..1]      (s0, L)
//   sumx   [EE]           @64
//   bgA    [EE]           @1088
//   betap  [HH][DD]       @2112   (atomic; zeroed by D1 block 0)
//   alphap [HH]           @3136
//   vsumh  [HH][DD]       @3200
//   partT  [EE][NCOL]     @8192
//   xT     [EE][RMAX]     @139264 (zero-padded rows r>=L)
//   qh     [HH][RMAX][DD] @270336
//   kTh    [HH][DD][RMAX] @401408
//   vh     [HH][RMAX][DD] @532480
// ---------------------------------------------------------------------------
#define OFF_SUMX  64
#define OFF_BGA   1088
#define OFF_BETA  2112
#define OFF_ALPHA 3136
#define OFF_VSUM  3200
#define OFF_PART  8192
#define OFF_XT    (OFF_PART + EE * NCOL)
#define OFF_QH    (OFF_XT + EE * RMAX)
#define OFF_KTH   (OFF_QH + HH * RMAX * DD)
#define OFF_VH    (OFF_KTH + HH * DD * RMAX)

__device__ __forceinline__ void seg_scan(const int* __restrict__ seg,
                                         const int* __restrict__ posp,
                                         int* sh, int& s0, int& L) {
    if (threadIdx.x == 0) { sh[0] = SS; sh[1] = -1; }
    __syncthreads();
    int sid = seg[posp[0]];
    int lmin = SS, lmax = -1;
    for (int i = threadIdx.x; i < SS; i += 256)
        if (seg[i] == sid) { lmin = min(lmin, i); lmax = max(lmax, i); }
#pragma unroll
    for (int off = 32; off; off >>= 1) {
        lmin = min(lmin, __shfl_xor(lmin, off));
        lmax = max(lmax, __shfl_xor(lmax, off));
    }
    if ((threadIdx.x & 63) == 0) { atomicMin(&sh[0], lmin); atomicMax(&sh[1], lmax); }
    __syncthreads();
    s0 = sh[0];
    L  = sh[1] - sh[0] + 1;
    if (L > RMAX) L = RMAX;
    if (L < 1)    L = 1;
}

// -------- D0: colsum -> partT (128 blk) || x-seg transpose -> xT (8 blk) ----
__global__ __launch_bounds__(256) void d0_kernel(
    const float* __restrict__ x, const int* __restrict__ seg,
    const int* __restrict__ posp, float* __restrict__ ws) {
    int bid = blockIdx.x, tid = threadIdx.x;
    if (bid < NCOL) {
        float* partT = ws + OFF_PART;
        int r0 = bid * (SS / NCOL);
        const float4* x4 = (const float4*)x;
        float4 a = make_float4(0.f, 0.f, 0.f, 0.f);
#pragma unroll 8
        for (int r = 0; r < SS / NCOL; ++r) {
            float4 v = x4[(size_t)(r0 + r) * 256 + tid];
            a.x += v.x; a.y += v.y; a.z += v.z; a.w += v.w;
        }
        partT[(size_t)(4 * tid + 0) * NCOL + bid] = a.x;
        partT[(size_t)(4 * tid + 1) * NCOL + bid] = a.y;
        partT[(size_t)(4 * tid + 2) * NCOL + bid] = a.z;
        partT[(size_t)(4 * tid + 3) * NCOL + bid] = a.w;
        return;
    }
    __shared__ float t[128 * 129];
    __shared__ int sh[2];
    int s0, L;
    seg_scan(seg, posp, sh, s0, L);
    int kb = bid - NCOL;
    if (kb == 0 && tid == 0) { ((int*)ws)[0] = s0; ((int*)ws)[1] = L; }
    int k0 = kb * 128;
    float* xT = ws + OFF_XT;
    for (int idx = tid; idx < 128 * 32; idx += 256) {
        int r = idx >> 5, c4 = idx & 31;
        float4 v = make_float4(0.f, 0.f, 0.f, 0.f);
        if (r < L) v = *(const float4*)(x + (size_t)(s0 + r) * EE + k0 + c4 * 4);
        t[r * 129 + c4 * 4 + 0] = v.x;
        t[r * 129 + c4 * 4 + 1] = v.y;
        t[r * 129 + c4 * 4 + 2] = v.z;
        t[r * 129 + c4 * 4 + 3] = v.w;
    }
    __syncthreads();
    for (int idx = tid; idx < 128 * 32; idx += 256) {
        int k = idx >> 5, r4 = idx & 31;
        float4 o;
        o.x = t[(r4 * 4 + 0) * 129 + k];
        o.y = t[(r4 * 4 + 1) * 129 + k];
        o.z = t[(r4 * 4 + 2) * 129 + k];
        o.w = t[(r4 * 4 + 3) * 129 + k];
        *(float4*)(xT + (size_t)(k0 + k) * RMAX + r4 * 4) = o;
    }
}

// -------- D1: sumx reduce + zero accum (8 blk) || QKV proj (192 blk) --------
// proj: block = 16 W rows x full K, staged into 64 KB LDS (coalesced float4,
// W read ONCE chip-wide). lane = row, 4 waves split K 4x256, both 64-row
// halves per lane. LDS aliased for the cross-wave reduce after compute.
__global__ __launch_bounds__(256) void d1_kernel(
    const float* __restrict__ Wq, const float* __restrict__ bq,
    const float* __restrict__ Wk, const float* __restrict__ bk,
    const float* __restrict__ Wv, const float* __restrict__ bv,
    float* __restrict__ ws) {
    int bid = blockIdx.x, tid = threadIdx.x;
    if (bid < NRED) {
        for (int rep = 0; rep < REP; ++rep) {
            if (bid == 0) {   // zero betap+alphap atomic accumulators
                for (int i = tid; i < 1088; i += 256) (ws + OFF_BETA)[i] = 0.f;
            }
            const float* partT = ws + OFF_PART;
            int e  = bid * 128 + (tid >> 1);
            int c0 = (tid & 1) * 64;
            const float4* p4 = (const float4*)(partT + (size_t)e * NCOL + c0);
            float4 s4 = make_float4(0.f, 0.f, 0.f, 0.f);
#pragma unroll
            for (int i = 0; i < 16; ++i) {
                float4 v = p4[i];
                s4.x += v.x; s4.y += v.y; s4.z += v.z; s4.w += v.w;
            }
            float s = s4.x + s4.y + s4.z + s4.w;
            s += __shfl_xor(s, 1);
            if ((tid & 1) == 0) (ws + OFF_SUMX)[e] = s;
            asm volatile("" ::: "memory");
        }
        return;
    }
    __shared__ float wsL[16 * EE];    // 64 KB W rows; aliased as reduce buffer
    int L  = ((const int*)ws)[1];
    int Lp = (L + 63) & ~63;
    int nh = Lp >> 6;                 // 1 or 2 row-halves
    int pid = bid - NRED;             // 0..191
    int m   = pid >> 6;               // 0..2
    int eb  = pid & 63;               // 0..63
    int e0  = eb * 16;
    const float* W = (m == 0) ? Wq : ((m == 1) ? Wk : Wv);
    const float* b = (m == 0) ? bq : ((m == 1) ? bk : bv);
    float* qh  = ws + OFF_QH;
    float* kTh = ws + OFF_KTH;
    float* vh  = ws + OFF_VH;
    int lane = tid & 63;
    int w4   = tid >> 6;
    int kbase = w4 * 256;
    int h = e0 >> 6;

    for (int rep = 0; rep < REP; ++rep) {
        __syncthreads();              // wsL reuse guard across reps
        {   // stage 16 contiguous W rows (64 KB), 16 float4/thread coalesced
            const float4* src = (const float4*)(W + (size_t)e0 * EE);
            float4* dst = (float4*)wsL;
#pragma unroll
            for (int i = 0; i < 16; ++i) dst[tid + i * 256] = src[tid + i * 256];
        }
        __syncthreads();

        const float* x0 = ws + OFF_XT + lane;
        float acc[2][16];
#pragma unroll
        for (int hh = 0; hh < 2; ++hh)
#pragma unroll
            for (int j = 0; j < 16; ++j) acc[hh][j] = 0.f;
        for (int kk = 0; kk < 256; kk += 8) {
            float xv0[8], xv1[8];
#pragma unroll
            for (int u = 0; u < 8; ++u)
                xv0[u] = x0[(size_t)(kbase + kk + u) * RMAX];
            if (nh == 2) {
#pragma unroll
                for (int u = 0; u < 8; ++u)
                    xv1[u] = x0[(size_t)(kbase + kk + u) * RMAX + 64];
            }
#pragma unroll
            for (int j = 0; j < 16; ++j) {
                const float4* wp = (const float4*)&wsL[j * EE + kbase + kk];
                float4 wa = wp[0], wb = wp[1];
                acc[0][j] += wa.x * xv0[0] + wa.y * xv0[1] + wa.z * xv0[2] + wa.w * xv0[3]
                           + wb.x * xv0[4] + wb.y * xv0[5] + wb.z * xv0[6] + wb.w * xv0[7];
                if (nh == 2)
                    acc[1][j] += wa.x * xv1[0] + wa.y * xv1[1] + wa.z * xv1[2] + wa.w * xv1[3]
                               + wb.x * xv1[4] + wb.y * xv1[5] + wb.z * xv1[6] + wb.w * xv1[7];
            }
        }

        for (int h2 = 0; h2 < nh; ++h2) {
            __syncthreads();
#pragma unroll
            for (int j = 0; j < 16; ++j)
                wsL[(w4 * 16 + j) * 66 + lane] = acc[h2][j];
            __syncthreads();
            int rg = h2 * 64 + lane;
#pragma unroll
            for (int jj = 0; jj < 4; ++jj) {
                int p = w4 * 4 + jj;
                float v = 0.f;
                if (rg < L)
                    v = wsL[(0 * 16 + p) * 66 + lane] + wsL[(1 * 16 + p) * 66 + lane]
                      + wsL[(2 * 16 + p) * 66 + lane] + wsL[(3 * 16 + p) * 66 + lane]
                      + b[e0 + p];
                int d0 = (e0 & 63) + p;
                if (m == 1) kTh[(size_t)(h * DD + d0) * RMAX + rg] = v;
                else        ((m == 0) ? qh : vh)[((size_t)h * RMAX + rg) * DD + d0] = v;
            }
        }
        asm volatile("" ::: "memory");
    }
}

// -------- D2: bgA (64) || vsumh (16) || attention, 1 wave per (r,h) (256) ----
__global__ __launch_bounds__(256) void d2_kernel(
    const float* __restrict__ Wv, const float* __restrict__ bv,
    float* __restrict__ ws) {
    __shared__ float qS[4 * 64];
    __shared__ float wS[4 * 128];
    __shared__ float vp_[4][64];
    const float* sumx = ws + OFF_SUMX;
    float* bgA    = ws + OFF_BGA;
    float* betap  = ws + OFF_BETA;
    float* alphap = ws + OFF_ALPHA;
    float* vsumh  = ws + OFF_VSUM;
    const float* qh  = ws + OFF_QH;
    const float* kTh = ws + OFF_KTH;
    const float* vh  = ws + OFF_VH;

    int bid = blockIdx.x, tid = threadIdx.x;
    int lane = tid & 63, wave = tid >> 6;
    int L  = ((const int*)ws)[1];
    int Lp = (L + 63) & ~63;

    if (bid < NBG) {
        int e = bid * 16 + (tid >> 4);
        int j = tid & 15;
        const float4* wr  = (const float4*)(Wv + (size_t)e * EE);
        const float4* sx4 = (const float4*)sumx;
        float p = 0.f;
#pragma unroll
        for (int jj = 0; jj < 16; ++jj) {
            float4 w = wr[jj * 16 + j], z = sx4[jj * 16 + j];
            p += w.x * z.x + w.y * z.y + w.z * z.z + w.w * z.w;
        }
        p += __shfl_xor(p, 8);
        p += __shfl_xor(p, 4);
        p += __shfl_xor(p, 2);
        p += __shfl_xor(p, 1);
        if (j == 0) bgA[e] = p + (float)SS * bv[e];
        return;
    }
    if (bid < NBG + NVS) {
        int h = bid - NBG;
        float s = 0.f;
        for (int t = wave; t < Lp; t += 4)
            s += vh[((size_t)h * RMAX + t) * DD + lane];
        vp_[wave][lane] = s;
        __syncthreads();
        if (wave == 0)
            vsumh[h * DD + lane] = vp_[0][lane] + vp_[1][lane]
                                 + vp_[2][lane] + vp_[3][lane];
        return;
    }

    int aid = bid - NBG - NVS;
    int gidbase = aid * 4 + wave;
    int pairs = L * HH;
    float* qSw = qS + wave * 64;
    float* wSw = wS + wave * 128;
    for (int wg = gidbase; wg < pairs; wg += NATT * 4) {
        int h = wg & (HH - 1);
        int r = wg >> 4;
        qSw[lane] = qh[((size_t)h * RMAX + r) * DD + lane];
        float s0 = 0.f, s1 = 0.f;
#pragma unroll
        for (int d = 0; d < 64; ++d) {
            float qd = qSw[d];
            const float* kr = kTh + (size_t)(h * DD + d) * RMAX;
            s0 += qd * kr[lane];
            s1 += qd * kr[64 + lane];
        }
        float v0 = (lane < L)      ? s0 : -3.0e38f;
        float v1 = (64 + lane < L) ? s1 : -3.0e38f;
        float m = fmaxf(0.f, fmaxf(v0, v1));
#pragma unroll
        for (int off = 32; off; off >>= 1) m = fmaxf(m, __shfl_xor(m, off));
        float w0 = (lane < L)      ? __expf(s0 - m) : 0.f;
        float w1 = (64 + lane < L) ? __expf(s1 - m) : 0.f;
        float Zl = w0 + w1;
#pragma unroll
        for (int off = 32; off; off >>= 1) Zl += __shfl_xor(Zl, off);
        float em = __expf(-m);
        float Z  = Zl + (float)(SS - L) * em;
        wSw[lane]      = w0;
        wSw[64 + lane] = w1;
        float acc = 0.f;
#pragma unroll 16
        for (int t = 0; t < Lp; ++t)
            acc += wSw[t] * vh[((size_t)h * RMAX + t) * DD + lane];
        float invZ = 1.0f / Z;
        atomicAdd(&betap[h * DD + lane], acc * invZ);
        if (lane == 0) atomicAdd(&alphap[h], em * invZ);
    }
}

// -------- D3: out[e] = bo[e] + Wo[e,:].(beta + alpha o (bgA - vsumh)) / L ----
__global__ __launch_bounds__(256) void d3_kernel(
    const float* __restrict__ Wo, const float* __restrict__ bo,
    const float* __restrict__ ws, float* __restrict__ out) {
    __shared__ float z[EE];
    int tid = threadIdx.x;
    int lane = tid & 63, wave = tid >> 6;
    int L = ((const int*)ws)[1];

    {
        int h = tid >> 4;
        float4 beta = ((const float4*)(ws + OFF_BETA))[tid];
        float  a    = (ws + OFF_ALPHA)[h];
        float4 g    = ((const float4*)(ws + OFF_BGA))[tid];
        float4 vs   = ((const float4*)(ws + OFF_VSUM))[tid];
        ((float4*)z)[tid] = make_float4(beta.x + a * (g.x - vs.x),
                                        beta.y + a * (g.y - vs.y),
                                        beta.z + a * (g.z - vs.z),
                                        beta.w + a * (g.w - vs.w));
    }
    __syncthreads();

    int e = blockIdx.x * 4 + wave;
    const float4* wr = (const float4*)(Wo + (size_t)e * EE);
    const float4* z4 = (const float4*)z;
    float p = 0.f;
#pragma unroll
    for (int it = 0; it < 4; ++it) {
        float4 w = wr[it * 64 + lane], zz = z4[it * 64 + lane];
        p += w.x * zz.x + w.y * zz.y + w.z * zz.z + w.w * zz.w;
    }
#pragma unroll
    for (int off = 32; off; off >>= 1) p += __shfl_xor(p, off);
    if (lane == 0) out[e] = bo[e] + p / (float)L;
}

extern "C" void kernel_launch(void* const* d_in, const int* in_sizes, int n_in,
                              void* d_out, int out_size, void* d_ws, size_t ws_size,
                              hipStream_t stream) {
    const float* x   = (const float*)d_in[0];
    const float* Wq  = (const float*)d_in[1];
    const float* bq  = (const float*)d_in[2];
    const float* Wk  = (const float*)d_in[3];
    const float* bk  = (const float*)d_in[4];
    const float* Wv  = (const float*)d_in[5];
    const float* bv  = (const float*)d_in[6];
    const float* Wo  = (const float*)d_in[7];
    const float* bo  = (const float*)d_in[8];
    const int*   seg = (const int*)d_in[9];
    const int*   pos = (const int*)d_in[10];
    float*       out = (float*)d_out;
    float*       ws  = (float*)d_ws;

    d0_kernel<<<NCOL + NTR, 256, 0, stream>>>(x, seg, pos, ws);
    d1_kernel<<<NRED + NPROJ, 256, 0, stream>>>(Wq, bq, Wk, bk, Wv, bv, ws);
    d2_kernel<<<NBG + NVS + NATT, 256, 0, stream>>>(Wv, bv, ws);
    d3_kernel<<<EE / 4, 256, 0, stream>>>(Wo, bo, ws, out);
}

// Round 17
// 80.199 us; speedup vs baseline: 9.5380x; 9.5380x over previous
//
#include <hip/hip_runtime.h>
#include <math.h>

#define SS 4096
#define EE 1024
#define HH 16
#define DD 64
#define RMAX 128
#define NCOL 128
#define NTR  8
#define NRED 8
#define NPROJ 384  // 3 m * 32 e-tiles(32e) * 4 K-chunks(256)
#define NREDB 96   // d1b reduce blocks: 3 m * 32 e-tiles
#define NBG 64
#define NVS 16
#define NATT 256

// ---------------------------------------------------------------------------
// ws float offsets. LESSONS: (r9/r10) no 4KB-strided ws reads; (r3) no BULK
// global atomics; (r5/r7) no software grid barriers; (r13) no shallow-flight
// staging; (r14) scalar W loads cap at 700 GB/s; (r16, measured) d1 was 47us
// warm: 64KB-LDS blocks -> 0.75/CU, LDS-broadcast-issue-bound. Fix: split-K,
// 32KB LDS, plain-store partials + tiny reduce dispatch.
//   meta   int[0..1]      (s0, L)
//   sumx   [EE]           @64
//   bgA    [EE]           @1088
//   betap  [HH][DD]       @2112   (atomic; zeroed by D1 block 0)
//   alphap [HH]           @3136
//   vsumh  [HH][DD]       @3200
//   partT  [EE][NCOL]     @8192
//   xT     [EE][RMAX]     @139264 (zero-padded rows r>=L)
//   qh     [HH][RMAX][DD] @270336
//   kTh    [HH][DD][RMAX] @401408
//   vh     [HH][RMAX][DD] @532480
//   ypart  [4][3][EE][RMAX] @663552  (proj K-chunk partials, 6 MB)
// ---------------------------------------------------------------------------
#define OFF_SUMX  64
#define OFF_BGA   1088
#define OFF_BETA  2112
#define OFF_ALPHA 3136
#define OFF_VSUM  3200
#define OFF_PART  8192
#define OFF_XT    (OFF_PART + EE * NCOL)
#define OFF_QH    (OFF_XT + EE * RMAX)
#define OFF_KTH   (OFF_QH + HH * RMAX * DD)
#define OFF_VH    (OFF_KTH + HH * DD * RMAX)
#define OFF_YP    (OFF_VH + HH * RMAX * DD)

__device__ __forceinline__ void seg_scan(const int* __restrict__ seg,
                                         const int* __restrict__ posp,
                                         int* sh, int& s0, int& L) {
    if (threadIdx.x == 0) { sh[0] = SS; sh[1] = -1; }
    __syncthreads();
    int sid = seg[posp[0]];
    int lmin = SS, lmax = -1;
    for (int i = threadIdx.x; i < SS; i += 256)
        if (seg[i] == sid) { lmin = min(lmin, i); lmax = max(lmax, i); }
#pragma unroll
    for (int off = 32; off; off >>= 1) {
        lmin = min(lmin, __shfl_xor(lmin, off));
        lmax = max(lmax, __shfl_xor(lmax, off));
    }
    if ((threadIdx.x & 63) == 0) { atomicMin(&sh[0], lmin); atomicMax(&sh[1], lmax); }
    __syncthreads();
    s0 = sh[0];
    L  = sh[1] - sh[0] + 1;
    if (L > RMAX) L = RMAX;
    if (L < 1)    L = 1;
}

// -------- D0: colsum -> partT (128 blk) || x-seg transpose -> xT (8 blk) ----
__global__ __launch_bounds__(256) void d0_kernel(
    const float* __restrict__ x, const int* __restrict__ seg,
    const int* __restrict__ posp, float* __restrict__ ws) {
    int bid = blockIdx.x, tid = threadIdx.x;
    if (bid < NCOL) {
        float* partT = ws + OFF_PART;
        int r0 = bid * (SS / NCOL);
        const float4* x4 = (const float4*)x;
        float4 a = make_float4(0.f, 0.f, 0.f, 0.f);
#pragma unroll 8
        for (int r = 0; r < SS / NCOL; ++r) {
            float4 v = x4[(size_t)(r0 + r) * 256 + tid];
            a.x += v.x; a.y += v.y; a.z += v.z; a.w += v.w;
        }
        partT[(size_t)(4 * tid + 0) * NCOL + bid] = a.x;
        partT[(size_t)(4 * tid + 1) * NCOL + bid] = a.y;
        partT[(size_t)(4 * tid + 2) * NCOL + bid] = a.z;
        partT[(size_t)(4 * tid + 3) * NCOL + bid] = a.w;
        return;
    }
    __shared__ float t[128 * 129];
    __shared__ int sh[2];
    int s0, L;
    seg_scan(seg, posp, sh, s0, L);
    int kb = bid - NCOL;
    if (kb == 0 && tid == 0) { ((int*)ws)[0] = s0; ((int*)ws)[1] = L; }
    int k0 = kb * 128;
    float* xT = ws + OFF_XT;
    for (int idx = tid; idx < 128 * 32; idx += 256) {
        int r = idx >> 5, c4 = idx & 31;
        float4 v = make_float4(0.f, 0.f, 0.f, 0.f);
        if (r < L) v = *(const float4*)(x + (size_t)(s0 + r) * EE + k0 + c4 * 4);
        t[r * 129 + c4 * 4 + 0] = v.x;
        t[r * 129 + c4 * 4 + 1] = v.y;
        t[r * 129 + c4 * 4 + 2] = v.z;
        t[r * 129 + c4 * 4 + 3] = v.w;
    }
    __syncthreads();
    for (int idx = tid; idx < 128 * 32; idx += 256) {
        int k = idx >> 5, r4 = idx & 31;
        float4 o;
        o.x = t[(r4 * 4 + 0) * 129 + k];
        o.y = t[(r4 * 4 + 1) * 129 + k];
        o.z = t[(r4 * 4 + 2) * 129 + k];
        o.w = t[(r4 * 4 + 3) * 129 + k];
        *(float4*)(xT + (size_t)(k0 + k) * RMAX + r4 * 4) = o;
    }
}

// -------- D1: sumx reduce + zero accum (8 blk) || split-K proj (384 blk) ----
// proj block = (m, 32-e tile, 256-k chunk). W chunk staged to 32 KB LDS
// (coalesced, read once chip-wide). Wave owns 8 e-rows; lane = row; both
// row-halves when Lp=128. Partials -> ypart[kc][m][e][r], coalesced stores.
__global__ __launch_bounds__(256) void d1_kernel(
    const float* __restrict__ Wq, const float* __restrict__ Wk,
    const float* __restrict__ Wv, float* __restrict__ ws) {
    int bid = blockIdx.x, tid = threadIdx.x;
    if (bid < NRED) {
        if (bid == 0) {   // zero betap+alphap atomic accumulators
            for (int i = tid; i < 1088; i += 256) (ws + OFF_BETA)[i] = 0.f;
        }
        const float* partT = ws + OFF_PART;
        int e  = bid * 128 + (tid >> 1);
        int c0 = (tid & 1) * 64;
        const float4* p4 = (const float4*)(partT + (size_t)e * NCOL + c0);
        float4 s4 = make_float4(0.f, 0.f, 0.f, 0.f);
#pragma unroll
        for (int i = 0; i < 16; ++i) {
            float4 v = p4[i];
            s4.x += v.x; s4.y += v.y; s4.z += v.z; s4.w += v.w;
        }
        float s = s4.x + s4.y + s4.z + s4.w;
        s += __shfl_xor(s, 1);
        if ((tid & 1) == 0) (ws + OFF_SUMX)[e] = s;
        return;
    }
    __shared__ float wsL[32 * 256];   // 32 KB: [e][k] W chunk
    int L  = ((const int*)ws)[1];
    int Lp = (L + 63) & ~63;
    int nh = Lp >> 6;
    int pid = bid - NRED;             // 0..383
    int kc  = pid & 3;
    int et  = (pid >> 2) & 31;
    int m   = pid >> 7;
    const float* W = (m == 0) ? Wq : ((m == 1) ? Wk : Wv);
    int k0 = kc * 256;

    {   // stage W[et*32 .. +32)[k0 .. +256) -> LDS [e][k], 8 float4/thread
#pragma unroll
        for (int i = 0; i < 8; ++i) {
            int idx = tid + i * 256;          // 0..2047
            int e = idx >> 6, k4 = idx & 63;
            float4 v = *(const float4*)(W + (size_t)(et * 32 + e) * EE + k0 + k4 * 4);
            *(float4*)&wsL[e * 256 + k4 * 4] = v;
        }
    }
    __syncthreads();

    int lane = tid & 63;
    int w4   = tid >> 6;
    int e0w  = w4 * 8;                // wave's first e within the tile
    const float* x0 = ws + OFF_XT + lane;
    float acc[2][8];
#pragma unroll
    for (int hh = 0; hh < 2; ++hh)
#pragma unroll
        for (int j = 0; j < 8; ++j) acc[hh][j] = 0.f;
    for (int kk = 0; kk < 256; kk += 8) {
        float xv0[8], xv1[8];
#pragma unroll
        for (int u = 0; u < 8; ++u)
            xv0[u] = x0[(size_t)(k0 + kk + u) * RMAX];
        if (nh == 2) {
#pragma unroll
            for (int u = 0; u < 8; ++u)
                xv1[u] = x0[(size_t)(k0 + kk + u) * RMAX + 64];
        }
#pragma unroll
        for (int j = 0; j < 8; ++j) {
            const float4* wp = (const float4*)&wsL[(e0w + j) * 256 + kk];
            float4 wa = wp[0], wb = wp[1];
            acc[0][j] += wa.x * xv0[0] + wa.y * xv0[1] + wa.z * xv0[2] + wa.w * xv0[3]
                       + wb.x * xv0[4] + wb.y * xv0[5] + wb.z * xv0[6] + wb.w * xv0[7];
            if (nh == 2)
                acc[1][j] += wa.x * xv1[0] + wa.y * xv1[1] + wa.z * xv1[2] + wa.w * xv1[3]
                           + wb.x * xv1[4] + wb.y * xv1[5] + wb.z * xv1[6] + wb.w * xv1[7];
        }
    }
    // partial stores: ypart[kc][m][e][r], lane(r)-contiguous
    float* yp = ws + OFF_YP + ((size_t)(kc * 3 + m) * EE) * RMAX;
#pragma unroll
    for (int j = 0; j < 8; ++j) {
        int e = et * 32 + e0w + j;
        yp[(size_t)e * RMAX + lane] = acc[0][j];
        if (nh == 2) yp[(size_t)e * RMAX + 64 + lane] = acc[1][j];
    }
}

// -------- D1b: reduce ypart -> qh / kTh / vh (+bias, r<L gate). 96 blk -----
__global__ __launch_bounds__(256) void d1b_kernel(
    const float* __restrict__ bq, const float* __restrict__ bk,
    const float* __restrict__ bv, float* __restrict__ ws) {
    int bid = blockIdx.x, tid = threadIdx.x;
    int L = ((const int*)ws)[1];
    int m  = bid / 32;
    int et = bid % 32;
    const float* b = (m == 0) ? bq : ((m == 1) ? bk : bv);
    float* qh  = ws + OFF_QH;
    float* kTh = ws + OFF_KTH;
    float* vh  = ws + OFF_VH;
    const float* yp = ws + OFF_YP;
    int r4 = (tid & 31) * 4;          // float4 along r
    int ee = tid >> 5;                // 0..7
#pragma unroll
    for (int ep = 0; ep < 4; ++ep) {
        int e = et * 32 + ep * 8 + ee;
        size_t base = (size_t)e * RMAX + r4;
        float4 s = make_float4(0.f, 0.f, 0.f, 0.f);
#pragma unroll
        for (int kc = 0; kc < 4; ++kc) {
            float4 v = *(const float4*)(yp + ((size_t)(kc * 3 + m) * EE) * RMAX + base);
            s.x += v.x; s.y += v.y; s.z += v.z; s.w += v.w;
        }
        float bb = b[e];
        float o[4] = {s.x + bb, s.y + bb, s.z + bb, s.w + bb};
#pragma unroll
        for (int i = 0; i < 4; ++i) if (r4 + i >= L) o[i] = 0.f;
        int h = e >> 6, d = e & 63;
        if (m == 1) {
            *(float4*)(kTh + (size_t)(h * DD + d) * RMAX + r4) =
                make_float4(o[0], o[1], o[2], o[3]);
        } else {
            float* y = (m == 0) ? qh : vh;
#pragma unroll
            for (int i = 0; i < 4; ++i)
                y[((size_t)h * RMAX + r4 + i) * DD + d] = o[i];
        }
    }
}

// -------- D2: bgA (64) || vsumh (16) || attention, 1 wave per (r,h) (256) ----
__global__ __launch_bounds__(256) void d2_kernel(
    const float* __restrict__ Wv, const float* __restrict__ bv,
    float* __restrict__ ws) {
    __shared__ float qS[4 * 64];
    __shared__ float wS[4 * 128];
    __shared__ float vp_[4][64];
    const float* sumx = ws + OFF_SUMX;
    float* bgA    = ws + OFF_BGA;
    float* betap  = ws + OFF_BETA;
    float* alphap = ws + OFF_ALPHA;
    float* vsumh  = ws + OFF_VSUM;
    const float* qh  = ws + OFF_QH;
    const float* kTh = ws + OFF_KTH;
    const float* vh  = ws + OFF_VH;

    int bid = blockIdx.x, tid = threadIdx.x;
    int lane = tid & 63, wave = tid >> 6;
    int L  = ((const int*)ws)[1];
    int Lp = (L + 63) & ~63;

    if (bid < NBG) {
        int e = bid * 16 + (tid >> 4);
        int j = tid & 15;
        const float4* wr  = (const float4*)(Wv + (size_t)e * EE);
        const float4* sx4 = (const float4*)sumx;
        float p = 0.f;
#pragma unroll
        for (int jj = 0; jj < 16; ++jj) {
            float4 w = wr[jj * 16 + j], z = sx4[jj * 16 + j];
            p += w.x * z.x + w.y * z.y + w.z * z.z + w.w * z.w;
        }
        p += __shfl_xor(p, 8);
        p += __shfl_xor(p, 4);
        p += __shfl_xor(p, 2);
        p += __shfl_xor(p, 1);
        if (j == 0) bgA[e] = p + (float)SS * bv[e];
        return;
    }
    if (bid < NBG + NVS) {
        int h = bid - NBG;
        float s = 0.f;
        for (int t = wave; t < Lp; t += 4)
            s += vh[((size_t)h * RMAX + t) * DD + lane];
        vp_[wave][lane] = s;
        __syncthreads();
        if (wave == 0)
            vsumh[h * DD + lane] = vp_[0][lane] + vp_[1][lane]
                                 + vp_[2][lane] + vp_[3][lane];
        return;
    }

    int aid = bid - NBG - NVS;
    int gidbase = aid * 4 + wave;
    int pairs = L * HH;
    float* qSw = qS + wave * 64;
    float* wSw = wS + wave * 128;
    for (int wg = gidbase; wg < pairs; wg += NATT * 4) {
        int h = wg & (HH - 1);
        int r = wg >> 4;
        qSw[lane] = qh[((size_t)h * RMAX + r) * DD + lane];
        float s0 = 0.f, s1 = 0.f;
#pragma unroll
        for (int d = 0; d < 64; ++d) {
            float qd = qSw[d];
            const float* kr = kTh + (size_t)(h * DD + d) * RMAX;
            s0 += qd * kr[lane];
            s1 += qd * kr[64 + lane];
        }
        float v0 = (lane < L)      ? s0 : -3.0e38f;
        float v1 = (64 + lane < L) ? s1 : -3.0e38f;
        float m = fmaxf(0.f, fmaxf(v0, v1));
#pragma unroll
        for (int off = 32; off; off >>= 1) m = fmaxf(m, __shfl_xor(m, off));
        float w0 = (lane < L)      ? __expf(s0 - m) : 0.f;
        float w1 = (64 + lane < L) ? __expf(s1 - m) : 0.f;
        float Zl = w0 + w1;
#pragma unroll
        for (int off = 32; off; off >>= 1) Zl += __shfl_xor(Zl, off);
        float em = __expf(-m);
        float Z  = Zl + (float)(SS - L) * em;
        wSw[lane]      = w0;
        wSw[64 + lane] = w1;
        float acc = 0.f;
#pragma unroll 16
        for (int t = 0; t < Lp; ++t)
            acc += wSw[t] * vh[((size_t)h * RMAX + t) * DD + lane];
        float invZ = 1.0f / Z;
        atomicAdd(&betap[h * DD + lane], acc * invZ);
        if (lane == 0) atomicAdd(&alphap[h], em * invZ);
    }
}

// -------- D3: out[e] = bo[e] + Wo[e,:].(beta + alpha o (bgA - vsumh)) / L ----
__global__ __launch_bounds__(256) void d3_kernel(
    const float* __restrict__ Wo, const float* __restrict__ bo,
    const float* __restrict__ ws, float* __restrict__ out) {
    __shared__ float z[EE];
    int tid = threadIdx.x;
    int lane = tid & 63, wave = tid >> 6;
    int L = ((const int*)ws)[1];

    {
        int h = tid >> 4;
        float4 beta = ((const float4*)(ws + OFF_BETA))[tid];
        float  a    = (ws + OFF_ALPHA)[h];
        float4 g    = ((const float4*)(ws + OFF_BGA))[tid];
        float4 vs   = ((const float4*)(ws + OFF_VSUM))[tid];
        ((float4*)z)[tid] = make_float4(beta.x + a * (g.x - vs.x),
                                        beta.y + a * (g.y - vs.y),
                                        beta.z + a * (g.z - vs.z),
                                        beta.w + a * (g.w - vs.w));
    }
    __syncthreads();

    int e = blockIdx.x * 4 + wave;
    const float4* wr = (const float4*)(Wo + (size_t)e * EE);
    const float4* z4 = (const float4*)z;
    float p = 0.f;
#pragma unroll
    for (int it = 0; it < 4; ++it) {
        float4 w = wr[it * 64 + lane], zz = z4[it * 64 + lane];
        p += w.x * zz.x + w.y * zz.y + w.z * zz.z + w.w * zz.w;
    }
#pragma unroll
    for (int off = 32; off; off >>= 1) p += __shfl_xor(p, off);
    if (lane == 0) out[e] = bo[e] + p / (float)L;
}

extern "C" void kernel_launch(void* const* d_in, const int* in_sizes, int n_in,
                              void* d_out, int out_size, void* d_ws, size_t ws_size,
                              hipStream_t stream) {
    const float* x   = (const float*)d_in[0];
    const float* Wq  = (const float*)d_in[1];
    const float* bq  = (const float*)d_in[2];
    const float* Wk  = (const float*)d_in[3];
    const float* bk  = (const float*)d_in[4];
    const float* Wv  = (const float*)d_in[5];
    const float* bv  = (const float*)d_in[6];
    const float* Wo  = (const float*)d_in[7];
    const float* bo  = (const float*)d_in[8];
    const int*   seg = (const int*)d_in[9];
    const int*   pos = (const int*)d_in[10];
    float*       out = (float*)d_out;
    float*       ws  = (float*)d_ws;

    d0_kernel<<<NCOL + NTR, 256, 0, stream>>>(x, seg, pos, ws);
    d1_kernel<<<NRED + NPROJ, 256, 0, stream>>>(Wq, Wk, Wv, ws);
    d1b_kernel<<<NREDB, 256, 0, stream>>>(bq, bk, bv, ws);
    d2_kernel<<<NBG + NVS + NATT, 256, 0, stream>>>(Wv, bv, ws);
    d3_kernel<<<EE / 4, 256, 0, stream>>>(Wo, bo, ws, out);
}

// Round 18
// 74.219 us; speedup vs baseline: 10.3066x; 1.0806x over previous
//
#include <hip/hip_runtime.h>
#include <math.h>

#define SS 4096
#define EE 1024
#define HH 16
#define DD 64
#define RMAX 128
#define NCOL 128
#define NTR  8
#define NRED 8
#define NPROJ 1536 // 3 m * 256 e-tiles(4e) * 2 r-tiles  (r12 structure, measured ~17us)
#define NBG 64
#define NVS 16
#define NATT 256

// ---------------------------------------------------------------------------
// ws float offsets. LESSONS: (r9/r10) no 4KB-strided ws reads; (r3) no BULK
// global atomics; (r5/r7) no software grid barriers; (r13) no shallow-flight
// staging; (r14) scalar W loads cap at 700 GB/s when TLP is low; (r17/r18,
// measured ledger) d1 variants: r12-style 1536-blk ping-pong-prefetch ~17us,
// 768-blk dual-half 41.7us, 192-blk 64KB-LDS 47us, split-K+reduce ~60us —
// TLP (6 blk/CU) + software-pipelined xv prefetch beat every "smarter" W
// staging scheme. Do not reduce proj block count below ~4/CU.
//   meta   int[0..1]      (s0, L)
//   sumx   [EE]           @64
//   bgA    [EE]           @1088
//   betap  [HH][DD]       @2112   (atomic; zeroed by D1 block 0)
//   alphap [HH]           @3136
//   vsumh  [HH][DD]       @3200
//   partT  [EE][NCOL]     @8192
//   xT     [EE][RMAX]     @139264 (zero-padded rows r>=L)
//   qh     [HH][RMAX][DD] @270336 (rows L..Lp-1 zeroed)
//   kTh    [HH][DD][RMAX] @401408 (cols L..Lp-1 zeroed)
//   vh     [HH][RMAX][DD] @532480 (rows L..Lp-1 zeroed)
// ---------------------------------------------------------------------------
#define OFF_SUMX  64
#define OFF_BGA   1088
#define OFF_BETA  2112
#define OFF_ALPHA 3136
#define OFF_VSUM  3200
#define OFF_PART  8192
#define OFF_XT    (OFF_PART + EE * NCOL)
#define OFF_QH    (OFF_XT + EE * RMAX)
#define OFF_KTH   (OFF_QH + HH * RMAX * DD)
#define OFF_VH    (OFF_KTH + HH * DD * RMAX)

__device__ __forceinline__ void seg_scan(const int* __restrict__ seg,
                                         const int* __restrict__ posp,
                                         int* sh, int& s0, int& L) {
    if (threadIdx.x == 0) { sh[0] = SS; sh[1] = -1; }
    __syncthreads();
    int sid = seg[posp[0]];
    int lmin = SS, lmax = -1;
    for (int i = threadIdx.x; i < SS; i += 256)
        if (seg[i] == sid) { lmin = min(lmin, i); lmax = max(lmax, i); }
#pragma unroll
    for (int off = 32; off; off >>= 1) {
        lmin = min(lmin, __shfl_xor(lmin, off));
        lmax = max(lmax, __shfl_xor(lmax, off));
    }
    if ((threadIdx.x & 63) == 0) { atomicMin(&sh[0], lmin); atomicMax(&sh[1], lmax); }
    __syncthreads();
    s0 = sh[0];
    L  = sh[1] - sh[0] + 1;
    if (L > RMAX) L = RMAX;
    if (L < 1)    L = 1;
}

// -------- D0: colsum -> partT (128 blk) || x-seg transpose -> xT (8 blk) ----
__global__ __launch_bounds__(256) void d0_kernel(
    const float* __restrict__ x, const int* __restrict__ seg,
    const int* __restrict__ posp, float* __restrict__ ws) {
    int bid = blockIdx.x, tid = threadIdx.x;
    if (bid < NCOL) {
        float* partT = ws + OFF_PART;
        int r0 = bid * (SS / NCOL);
        const float4* x4 = (const float4*)x;
        float4 a = make_float4(0.f, 0.f, 0.f, 0.f);
#pragma unroll 8
        for (int r = 0; r < SS / NCOL; ++r) {
            float4 v = x4[(size_t)(r0 + r) * 256 + tid];
            a.x += v.x; a.y += v.y; a.z += v.z; a.w += v.w;
        }
        partT[(size_t)(4 * tid + 0) * NCOL + bid] = a.x;
        partT[(size_t)(4 * tid + 1) * NCOL + bid] = a.y;
        partT[(size_t)(4 * tid + 2) * NCOL + bid] = a.z;
        partT[(size_t)(4 * tid + 3) * NCOL + bid] = a.w;
        return;
    }
    __shared__ float t[128 * 129];
    __shared__ int sh[2];
    int s0, L;
    seg_scan(seg, posp, sh, s0, L);
    int kb = bid - NCOL;
    if (kb == 0 && tid == 0) { ((int*)ws)[0] = s0; ((int*)ws)[1] = L; }
    int k0 = kb * 128;
    float* xT = ws + OFF_XT;
    for (int idx = tid; idx < 128 * 32; idx += 256) {
        int r = idx >> 5, c4 = idx & 31;
        float4 v = make_float4(0.f, 0.f, 0.f, 0.f);
        if (r < L) v = *(const float4*)(x + (size_t)(s0 + r) * EE + k0 + c4 * 4);
        t[r * 129 + c4 * 4 + 0] = v.x;
        t[r * 129 + c4 * 4 + 1] = v.y;
        t[r * 129 + c4 * 4 + 2] = v.z;
        t[r * 129 + c4 * 4 + 3] = v.w;
    }
    __syncthreads();
    for (int idx = tid; idx < 128 * 32; idx += 256) {
        int k = idx >> 5, r4 = idx & 31;
        float4 o;
        o.x = t[(r4 * 4 + 0) * 129 + k];
        o.y = t[(r4 * 4 + 1) * 129 + k];
        o.z = t[(r4 * 4 + 2) * 129 + k];
        o.w = t[(r4 * 4 + 3) * 129 + k];
        *(float4*)(xT + (size_t)(k0 + k) * RMAX + r4 * 4) = o;
    }
}

// -------- D1: sumx reduce + zero accum (8 blk) || QKV projection (1536 blk) --
// r12 structure (measured ~17us): 4 W-rows/block, lane = r, 4 waves split K,
// xv0/xv1 ping-pong prefetch of xT columns, wave-uniform scalar W loads,
// 6 blocks/CU TLP. Do not "simplify" — see ledger note above.
__global__ __launch_bounds__(256) void d1_kernel(
    const float* __restrict__ Wq, const float* __restrict__ bq,
    const float* __restrict__ Wk, const float* __restrict__ bk,
    const float* __restrict__ Wv, const float* __restrict__ bv,
    float* __restrict__ ws) {
    int bid = blockIdx.x, tid = threadIdx.x;
    if (bid < NRED) {
        if (bid == 0) {   // zero betap+alphap atomic accumulators
            for (int i = tid; i < 1088; i += 256) (ws + OFF_BETA)[i] = 0.f;
        }
        const float* partT = ws + OFF_PART;
        int e  = bid * 128 + (tid >> 1);
        int c0 = (tid & 1) * 64;
        const float4* p4 = (const float4*)(partT + (size_t)e * NCOL + c0);
        float4 s4 = make_float4(0.f, 0.f, 0.f, 0.f);
#pragma unroll
        for (int i = 0; i < 16; ++i) {
            float4 v = p4[i];
            s4.x += v.x; s4.y += v.y; s4.z += v.z; s4.w += v.w;
        }
        float s = s4.x + s4.y + s4.z + s4.w;
        s += __shfl_xor(s, 1);
        if ((tid & 1) == 0) (ws + OFF_SUMX)[e] = s;
        return;
    }
    __shared__ float red[16 * 66];
    int L  = ((const int*)ws)[1];
    int Lp = (L + 63) & ~63;
    int pid = bid - NRED;
    int m   = pid / 512;          // 0..2
    int rem = pid - m * 512;
    int eb  = rem >> 1;           // 0..255 (4 e each)
    int rt  = rem & 1;
    int r0  = rt * 64;
    if (r0 >= Lp) return;
    int e0 = eb * 4;
    const float* W = (m == 0) ? Wq : ((m == 1) ? Wk : Wv);
    const float* b = (m == 0) ? bq : ((m == 1) ? bk : bv);
    int lane = tid & 63;
    int w4 = __builtin_amdgcn_readfirstlane(tid >> 6);   // wave id, uniform
    const float* xcol = ws + OFF_XT + r0 + lane;
    int kbase = w4 * 256;
    const float* wr0 = W + (size_t)e0 * EE + kbase;      // uniform
    float acc0 = 0.f, acc1 = 0.f, acc2 = 0.f, acc3 = 0.f;
    float xv0[8], xv1[8];
#pragma unroll
    for (int u = 0; u < 8; ++u) xv0[u] = xcol[(size_t)(kbase + u) * RMAX];
    for (int kk = 0; kk < 256; kk += 16) {
        // prefetch second half while first computes
#pragma unroll
        for (int u = 0; u < 8; ++u)
            xv1[u] = xcol[(size_t)(kbase + kk + 8 + u) * RMAX];
#pragma unroll
        for (int u = 0; u < 8; ++u) {
            float w0 = wr0[0 * EE + kk + u];
            float w1 = wr0[1 * EE + kk + u];
            float w2 = wr0[2 * EE + kk + u];
            float w3 = wr0[3 * EE + kk + u];
            acc0 += xv0[u] * w0; acc1 += xv0[u] * w1;
            acc2 += xv0[u] * w2; acc3 += xv0[u] * w3;
        }
        // prefetch next iteration's first half (tail loads land in ws, unused)
#pragma unroll
        for (int u = 0; u < 8; ++u)
            xv0[u] = xcol[(size_t)(kbase + kk + 16 + u) * RMAX];
#pragma unroll
        for (int u = 0; u < 8; ++u) {
            float w0 = wr0[0 * EE + kk + 8 + u];
            float w1 = wr0[1 * EE + kk + 8 + u];
            float w2 = wr0[2 * EE + kk + 8 + u];
            float w3 = wr0[3 * EE + kk + 8 + u];
            acc0 += xv1[u] * w0; acc1 += xv1[u] * w1;
            acc2 += xv1[u] * w2; acc3 += xv1[u] * w3;
        }
    }
    red[(w4 * 4 + 0) * 66 + lane] = acc0;
    red[(w4 * 4 + 1) * 66 + lane] = acc1;
    red[(w4 * 4 + 2) * 66 + lane] = acc2;
    red[(w4 * 4 + 3) * 66 + lane] = acc3;
    __syncthreads();
    int p  = tid >> 6;            // wave -> e index (4 each)
    int rg = r0 + lane;
    float* qh  = ws + OFF_QH;
    float* kTh = ws + OFF_KTH;
    float* vh  = ws + OFF_VH;
    int h = e0 >> 6, d0 = (e0 & 63) + p;
    float v = 0.f;
    if (rg < L)
        v = red[(0 * 4 + p) * 66 + lane] + red[(1 * 4 + p) * 66 + lane]
          + red[(2 * 4 + p) * 66 + lane] + red[(3 * 4 + p) * 66 + lane]
          + b[e0 + p];
    if (m == 1) kTh[(size_t)(h * DD + d0) * RMAX + rg] = v;
    else        ((m == 0) ? qh : vh)[((size_t)h * RMAX + rg) * DD + d0] = v;
}

// -------- D2: bgA (64) || vsumh (16) || attention, 1 wave per (r,h) (256) ----
__global__ __launch_bounds__(256) void d2_kernel(
    const float* __restrict__ Wv, const float* __restrict__ bv,
    float* __restrict__ ws) {
    __shared__ float qS[4 * 64];
    __shared__ float wS[4 * 128];
    __shared__ float vp_[4][64];
    const float* sumx = ws + OFF_SUMX;
    float* bgA    = ws + OFF_BGA;
    float* betap  = ws + OFF_BETA;
    float* alphap = ws + OFF_ALPHA;
    float* vsumh  = ws + OFF_VSUM;
    const float* qh  = ws + OFF_QH;
    const float* kTh = ws + OFF_KTH;
    const float* vh  = ws + OFF_VH;

    int bid = blockIdx.x, tid = threadIdx.x;
    int lane = tid & 63, wave = tid >> 6;
    int L  = ((const int*)ws)[1];
    int Lp = (L + 63) & ~63;

    if (bid < NBG) {
        int e = bid * 16 + (tid >> 4);
        int j = tid & 15;
        const float4* wr  = (const float4*)(Wv + (size_t)e * EE);
        const float4* sx4 = (const float4*)sumx;
        float p = 0.f;
#pragma unroll
        for (int jj = 0; jj < 16; ++jj) {
            float4 w = wr[jj * 16 + j], z = sx4[jj * 16 + j];
            p += w.x * z.x + w.y * z.y + w.z * z.z + w.w * z.w;
        }
        p += __shfl_xor(p, 8);
        p += __shfl_xor(p, 4);
        p += __shfl_xor(p, 2);
        p += __shfl_xor(p, 1);
        if (j == 0) bgA[e] = p + (float)SS * bv[e];
        return;
    }
    if (bid < NBG + NVS) {
        int h = bid - NBG;
        float s = 0.f;
        for (int t = wave; t < Lp; t += 4)
            s += vh[((size_t)h * RMAX + t) * DD + lane];
        vp_[wave][lane] = s;
        __syncthreads();
        if (wave == 0)
            vsumh[h * DD + lane] = vp_[0][lane] + vp_[1][lane]
                                 + vp_[2][lane] + vp_[3][lane];
        return;
    }

    int aid = bid - NBG - NVS;
    int gidbase = aid * 4 + wave;
    int pairs = L * HH;
    float* qSw = qS + wave * 64;
    float* wSw = wS + wave * 128;
    for (int wg = gidbase; wg < pairs; wg += NATT * 4) {
        int h = wg & (HH - 1);
        int r = wg >> 4;
        qSw[lane] = qh[((size_t)h * RMAX + r) * DD + lane];
        float s0 = 0.f, s1 = 0.f;
#pragma unroll
        for (int d = 0; d < 64; ++d) {
            float qd = qSw[d];
            const float* kr = kTh + (size_t)(h * DD + d) * RMAX;
            s0 += qd * kr[lane];
            s1 += qd * kr[64 + lane];
        }
        float v0 = (lane < L)      ? s0 : -3.0e38f;
        float v1 = (64 + lane < L) ? s1 : -3.0e38f;
        float m = fmaxf(0.f, fmaxf(v0, v1));
#pragma unroll
        for (int off = 32; off; off >>= 1) m = fmaxf(m, __shfl_xor(m, off));
        float w0 = (lane < L)      ? __expf(s0 - m) : 0.f;
        float w1 = (64 + lane < L) ? __expf(s1 - m) : 0.f;
        float Zl = w0 + w1;
#pragma unroll
        for (int off = 32; off; off >>= 1) Zl += __shfl_xor(Zl, off);
        float em = __expf(-m);
        float Z  = Zl + (float)(SS - L) * em;
        wSw[lane]      = w0;
        wSw[64 + lane] = w1;
        float acc = 0.f;
#pragma unroll 16
        for (int t = 0; t < Lp; ++t)
            acc += wSw[t] * vh[((size_t)h * RMAX + t) * DD + lane];
        float invZ = 1.0f / Z;
        atomicAdd(&betap[h * DD + lane], acc * invZ);
        if (lane == 0) atomicAdd(&alphap[h], em * invZ);
    }
}

// -------- D3: out[e] = bo[e] + Wo[e,:].(beta + alpha o (bgA - vsumh)) / L ----
__global__ __launch_bounds__(256) void d3_kernel(
    const float* __restrict__ Wo, const float* __restrict__ bo,
    const float* __restrict__ ws, float* __restrict__ out) {
    __shared__ float z[EE];
    int tid = threadIdx.x;
    int lane = tid & 63, wave = tid >> 6;
    int L = ((const int*)ws)[1];

    {
        int h = tid >> 4;
        float4 beta = ((const float4*)(ws + OFF_BETA))[tid];
        float  a    = (ws + OFF_ALPHA)[h];
        float4 g    = ((const float4*)(ws + OFF_BGA))[tid];
        float4 vs   = ((const float4*)(ws + OFF_VSUM))[tid];
        ((float4*)z)[tid] = make_float4(beta.x + a * (g.x - vs.x),
                                        beta.y + a * (g.y - vs.y),
                                        beta.z + a * (g.z - vs.z),
                                        beta.w + a * (g.w - vs.w));
    }
    __syncthreads();

    int e = blockIdx.x * 4 + wave;
    const float4* wr = (const float4*)(Wo + (size_t)e * EE);
    const float4* z4 = (const float4*)z;
    float p = 0.f;
#pragma unroll
    for (int it = 0; it < 4; ++it) {
        float4 w = wr[it * 64 + lane], zz = z4[it * 64 + lane];
        p += w.x * zz.x + w.y * zz.y + w.z * zz.z + w.w * zz.w;
    }
#pragma unroll
    for (int off = 32; off; off >>= 1) p += __shfl_xor(p, off);
    if (lane == 0) out[e] = bo[e] + p / (float)L;
}

extern "C" void kernel_launch(void* const* d_in, const int* in_sizes, int n_in,
                              void* d_out, int out_size, void* d_ws, size_t ws_size,
                              hipStream_t stream) {
    const float* x   = (const float*)d_in[0];
    const float* Wq  = (const float*)d_in[1];
    const float* bq  = (const float*)d_in[2];
    const float* Wk  = (const float*)d_in[3];
    const float* bk  = (const float*)d_in[4];
    const float* Wv  = (const float*)d_in[5];
    const float* bv  = (const float*)d_in[6];
    const float* Wo  = (const float*)d_in[7];
    const float* bo  = (const float*)d_in[8];
    const int*   seg = (const int*)d_in[9];
    const int*   pos = (const int*)d_in[10];
    float*       out = (float*)d_out;
    float*       ws  = (float*)d_ws;

    d0_kernel<<<NCOL + NTR, 256, 0, stream>>>(x, seg, pos, ws);
    d1_kernel<<<NRED + NPROJ, 256, 0, stream>>>(Wq, bq, Wk, bk, Wv, bv, ws);
    d2_kernel<<<NBG + NVS + NATT, 256, 0, stream>>>(Wv, bv, ws);
    d3_kernel<<<EE / 4, 256, 0, stream>>>(Wo, bo, ws, out);
}

// Round 19
// 70.848 us; speedup vs baseline: 10.7969x; 1.0476x over previous
//
#include <hip/hip_runtime.h>
#include <math.h>

#define SS 4096
#define EE 1024
#define HH 16
#define DD 64
#define RMAX 128
#define NCOL 128
#define NTR  8
#define NRED 8
#define NPROJ 1536 // 3 m * 256 e-tiles(4e) * 2 r-tiles; rt in HIGH bit (XCD pairing)
#define NBG 64
#define NVS 16
#define NATT 256

// ---------------------------------------------------------------------------
// ws float offsets. LESSONS: (r9/r10) no 4KB-strided ws reads; (r3) no BULK
// global atomics; (r5/r7) no software grid barriers; (r13) no shallow-flight
// staging; (r14/r16/r18 ledger) d1 proj: r12-style 1536-blk ping-pong ~41.7us
// measured — FETCH 25.9MB at ~700GB/s scalar-path => fetch-bound; low-TLP
// "fixes" (768/192 blk) were worse (39-47us). Keep TLP >= 6 blk/CU.
// (r19) rt moved to blockIdx HIGH bit so both blocks sharing a W slice land
// on the SAME XCD (768%8==0) -> second fetch L2-hits, W HBM traffic halves.
//   meta   int[0..1]      (s0, L)
//   sumx   [EE]           @64
//   bgA    [EE]           @1088
//   betap  [HH][DD]       @2112   (atomic; zeroed by D1 block 0)
//   alphap [HH]           @3136
//   vsumh  [HH][DD]       @3200
//   partT  [EE][NCOL]     @8192
//   xT     [EE][RMAX]     @139264 (zero-padded rows r>=L)
//   qh     [HH][RMAX][DD] @270336 (rows L..Lp-1 zeroed)
//   kTh    [HH][DD][RMAX] @401408 (cols L..Lp-1 zeroed)
//   vh     [HH][RMAX][DD] @532480 (rows L..Lp-1 zeroed)
// ---------------------------------------------------------------------------
#define OFF_SUMX  64
#define OFF_BGA   1088
#define OFF_BETA  2112
#define OFF_ALPHA 3136
#define OFF_VSUM  3200
#define OFF_PART  8192
#define OFF_XT    (OFF_PART + EE * NCOL)
#define OFF_QH    (OFF_XT + EE * RMAX)
#define OFF_KTH   (OFF_QH + HH * RMAX * DD)
#define OFF_VH    (OFF_KTH + HH * DD * RMAX)

__device__ __forceinline__ void seg_scan(const int* __restrict__ seg,
                                         const int* __restrict__ posp,
                                         int* sh, int& s0, int& L) {
    if (threadIdx.x == 0) { sh[0] = SS; sh[1] = -1; }
    __syncthreads();
    int sid = seg[posp[0]];
    int lmin = SS, lmax = -1;
    for (int i = threadIdx.x; i < SS; i += 256)
        if (seg[i] == sid) { lmin = min(lmin, i); lmax = max(lmax, i); }
#pragma unroll
    for (int off = 32; off; off >>= 1) {
        lmin = min(lmin, __shfl_xor(lmin, off));
        lmax = max(lmax, __shfl_xor(lmax, off));
    }
    if ((threadIdx.x & 63) == 0) { atomicMin(&sh[0], lmin); atomicMax(&sh[1], lmax); }
    __syncthreads();
    s0 = sh[0];
    L  = sh[1] - sh[0] + 1;
    if (L > RMAX) L = RMAX;
    if (L < 1)    L = 1;
}

// -------- D0: colsum -> partT (128 blk) || x-seg transpose -> xT (8 blk) ----
__global__ __launch_bounds__(256) void d0_kernel(
    const float* __restrict__ x, const int* __restrict__ seg,
    const int* __restrict__ posp, float* __restrict__ ws) {
    int bid = blockIdx.x, tid = threadIdx.x;
    if (bid < NCOL) {
        float* partT = ws + OFF_PART;
        int r0 = bid * (SS / NCOL);
        const float4* x4 = (const float4*)x;
        float4 a = make_float4(0.f, 0.f, 0.f, 0.f);
#pragma unroll 8
        for (int r = 0; r < SS / NCOL; ++r) {
            float4 v = x4[(size_t)(r0 + r) * 256 + tid];
            a.x += v.x; a.y += v.y; a.z += v.z; a.w += v.w;
        }
        partT[(size_t)(4 * tid + 0) * NCOL + bid] = a.x;
        partT[(size_t)(4 * tid + 1) * NCOL + bid] = a.y;
        partT[(size_t)(4 * tid + 2) * NCOL + bid] = a.z;
        partT[(size_t)(4 * tid + 3) * NCOL + bid] = a.w;
        return;
    }
    __shared__ float t[128 * 129];
    __shared__ int sh[2];
    int s0, L;
    seg_scan(seg, posp, sh, s0, L);
    int kb = bid - NCOL;
    if (kb == 0 && tid == 0) { ((int*)ws)[0] = s0; ((int*)ws)[1] = L; }
    int k0 = kb * 128;
    float* xT = ws + OFF_XT;
    for (int idx = tid; idx < 128 * 32; idx += 256) {
        int r = idx >> 5, c4 = idx & 31;
        float4 v = make_float4(0.f, 0.f, 0.f, 0.f);
        if (r < L) v = *(const float4*)(x + (size_t)(s0 + r) * EE + k0 + c4 * 4);
        t[r * 129 + c4 * 4 + 0] = v.x;
        t[r * 129 + c4 * 4 + 1] = v.y;
        t[r * 129 + c4 * 4 + 2] = v.z;
        t[r * 129 + c4 * 4 + 3] = v.w;
    }
    __syncthreads();
    for (int idx = tid; idx < 128 * 32; idx += 256) {
        int k = idx >> 5, r4 = idx & 31;
        float4 o;
        o.x = t[(r4 * 4 + 0) * 129 + k];
        o.y = t[(r4 * 4 + 1) * 129 + k];
        o.z = t[(r4 * 4 + 2) * 129 + k];
        o.w = t[(r4 * 4 + 3) * 129 + k];
        *(float4*)(xT + (size_t)(k0 + k) * RMAX + r4 * 4) = o;
    }
}

// -------- D1: sumx reduce + zero accum (8 blk) || QKV projection (1536 blk) --
// r12 structure + rt-high-bit XCD pairing. 4 W-rows/block, lane = r, 4 waves
// split K, xv0/xv1 ping-pong prefetch, wave-uniform scalar W loads.
__global__ __launch_bounds__(256) void d1_kernel(
    const float* __restrict__ Wq, const float* __restrict__ bq,
    const float* __restrict__ Wk, const float* __restrict__ bk,
    const float* __restrict__ Wv, const float* __restrict__ bv,
    float* __restrict__ ws) {
    int bid = blockIdx.x, tid = threadIdx.x;
    if (bid < NRED) {
        if (bid == 0) {   // zero betap+alphap atomic accumulators
            for (int i = tid; i < 1088; i += 256) (ws + OFF_BETA)[i] = 0.f;
        }
        const float* partT = ws + OFF_PART;
        int e  = bid * 128 + (tid >> 1);
        int c0 = (tid & 1) * 64;
        const float4* p4 = (const float4*)(partT + (size_t)e * NCOL + c0);
        float4 s4 = make_float4(0.f, 0.f, 0.f, 0.f);
#pragma unroll
        for (int i = 0; i < 16; ++i) {
            float4 v = p4[i];
            s4.x += v.x; s4.y += v.y; s4.z += v.z; s4.w += v.w;
        }
        float s = s4.x + s4.y + s4.z + s4.w;
        s += __shfl_xor(s, 1);
        if ((tid & 1) == 0) (ws + OFF_SUMX)[e] = s;
        return;
    }
    __shared__ float red[16 * 66];
    int L  = ((const int*)ws)[1];
    int Lp = (L + 63) & ~63;
    int pid = bid - NRED;         // 0..1535
    // rt in HIGH position: blocks p and p+768 share a W slice AND an XCD
    // (768 % 8 == 0 -> same blockIdx%8 -> same XCD; second fetch L2-hits).
    int rt  = (pid >= 768) ? 1 : 0;
    int rem = pid - rt * 768;     // 0..767
    int m   = rem >> 8;           // 0..2
    int eb  = rem & 255;          // 0..255 (4 e each)
    int r0  = rt * 64;
    if (r0 >= Lp) return;
    int e0 = eb * 4;
    const float* W = (m == 0) ? Wq : ((m == 1) ? Wk : Wv);
    const float* b = (m == 0) ? bq : ((m == 1) ? bk : bv);
    int lane = tid & 63;
    int w4 = __builtin_amdgcn_readfirstlane(tid >> 6);   // wave id, uniform
    const float* xcol = ws + OFF_XT + r0 + lane;
    int kbase = w4 * 256;
    const float* wr0 = W + (size_t)e0 * EE + kbase;      // uniform
    float acc0 = 0.f, acc1 = 0.f, acc2 = 0.f, acc3 = 0.f;
    float xv0[8], xv1[8];
#pragma unroll
    for (int u = 0; u < 8; ++u) xv0[u] = xcol[(size_t)(kbase + u) * RMAX];
    for (int kk = 0; kk < 256; kk += 16) {
        // prefetch second half while first computes
#pragma unroll
        for (int u = 0; u < 8; ++u)
            xv1[u] = xcol[(size_t)(kbase + kk + 8 + u) * RMAX];
#pragma unroll
        for (int u = 0; u < 8; ++u) {
            float w0 = wr0[0 * EE + kk + u];
            float w1 = wr0[1 * EE + kk + u];
            float w2 = wr0[2 * EE + kk + u];
            float w3 = wr0[3 * EE + kk + u];
            acc0 += xv0[u] * w0; acc1 += xv0[u] * w1;
            acc2 += xv0[u] * w2; acc3 += xv0[u] * w3;
        }
        // prefetch next iteration's first half (tail loads land in ws, unused)
#pragma unroll
        for (int u = 0; u < 8; ++u)
            xv0[u] = xcol[(size_t)(kbase + kk + 16 + u) * RMAX];
#pragma unroll
        for (int u = 0; u < 8; ++u) {
            float w0 = wr0[0 * EE + kk + 8 + u];
            float w1 = wr0[1 * EE + kk + 8 + u];
            float w2 = wr0[2 * EE + kk + 8 + u];
            float w3 = wr0[3 * EE + kk + 8 + u];
            acc0 += xv1[u] * w0; acc1 += xv1[u] * w1;
            acc2 += xv1[u] * w2; acc3 += xv1[u] * w3;
        }
    }
    red[(w4 * 4 + 0) * 66 + lane] = acc0;
    red[(w4 * 4 + 1) * 66 + lane] = acc1;
    red[(w4 * 4 + 2) * 66 + lane] = acc2;
    red[(w4 * 4 + 3) * 66 + lane] = acc3;
    __syncthreads();
    int p  = tid >> 6;            // wave -> e index (4 each)
    int rg = r0 + lane;
    float* qh  = ws + OFF_QH;
    float* kTh = ws + OFF_KTH;
    float* vh  = ws + OFF_VH;
    int h = e0 >> 6, d0 = (e0 & 63) + p;
    float v = 0.f;
    if (rg < L)
        v = red[(0 * 4 + p) * 66 + lane] + red[(1 * 4 + p) * 66 + lane]
          + red[(2 * 4 + p) * 66 + lane] + red[(3 * 4 + p) * 66 + lane]
          + b[e0 + p];
    if (m == 1) kTh[(size_t)(h * DD + d0) * RMAX + rg] = v;
    else        ((m == 0) ? qh : vh)[((size_t)h * RMAX + rg) * DD + d0] = v;
}

// -------- D2: bgA (64) || vsumh (16) || attention, 1 wave per (r,h) (256) ----
__global__ __launch_bounds__(256) void d2_kernel(
    const float* __restrict__ Wv, const float* __restrict__ bv,
    float* __restrict__ ws) {
    __shared__ float qS[4 * 64];
    __shared__ float wS[4 * 128];
    __shared__ float vp_[4][64];
    const float* sumx = ws + OFF_SUMX;
    float* bgA    = ws + OFF_BGA;
    float* betap  = ws + OFF_BETA;
    float* alphap = ws + OFF_ALPHA;
    float* vsumh  = ws + OFF_VSUM;
    const float* qh  = ws + OFF_QH;
    const float* kTh = ws + OFF_KTH;
    const float* vh  = ws + OFF_VH;

    int bid = blockIdx.x, tid = threadIdx.x;
    int lane = tid & 63, wave = tid >> 6;
    int L  = ((const int*)ws)[1];
    int Lp = (L + 63) & ~63;

    if (bid < NBG) {
        int e = bid * 16 + (tid >> 4);
        int j = tid & 15;
        const float4* wr  = (const float4*)(Wv + (size_t)e * EE);
        const float4* sx4 = (const float4*)sumx;
        float p = 0.f;
#pragma unroll
        for (int jj = 0; jj < 16; ++jj) {
            float4 w = wr[jj * 16 + j], z = sx4[jj * 16 + j];
            p += w.x * z.x + w.y * z.y + w.z * z.z + w.w * z.w;
        }
        p += __shfl_xor(p, 8);
        p += __shfl_xor(p, 4);
        p += __shfl_xor(p, 2);
        p += __shfl_xor(p, 1);
        if (j == 0) bgA[e] = p + (float)SS * bv[e];
        return;
    }
    if (bid < NBG + NVS) {
        int h = bid - NBG;
        float s = 0.f;
        for (int t = wave; t < Lp; t += 4)
            s += vh[((size_t)h * RMAX + t) * DD + lane];
        vp_[wave][lane] = s;
        __syncthreads();
        if (wave == 0)
            vsumh[h * DD + lane] = vp_[0][lane] + vp_[1][lane]
                                 + vp_[2][lane] + vp_[3][lane];
        return;
    }

    int aid = bid - NBG - NVS;
    int gidbase = aid * 4 + wave;
    int pairs = L * HH;
    float* qSw = qS + wave * 64;
    float* wSw = wS + wave * 128;
    for (int wg = gidbase; wg < pairs; wg += NATT * 4) {
        int h = wg & (HH - 1);
        int r = wg >> 4;
        qSw[lane] = qh[((size_t)h * RMAX + r) * DD + lane];
        float s0 = 0.f, s1 = 0.f;
#pragma unroll
        for (int d = 0; d < 64; ++d) {
            float qd = qSw[d];
            const float* kr = kTh + (size_t)(h * DD + d) * RMAX;
            s0 += qd * kr[lane];
            s1 += qd * kr[64 + lane];
        }
        float v0 = (lane < L)      ? s0 : -3.0e38f;
        float v1 = (64 + lane < L) ? s1 : -3.0e38f;
        float m = fmaxf(0.f, fmaxf(v0, v1));
#pragma unroll
        for (int off = 32; off; off >>= 1) m = fmaxf(m, __shfl_xor(m, off));
        float w0 = (lane < L)      ? __expf(s0 - m) : 0.f;
        float w1 = (64 + lane < L) ? __expf(s1 - m) : 0.f;
        float Zl = w0 + w1;
#pragma unroll
        for (int off = 32; off; off >>= 1) Zl += __shfl_xor(Zl, off);
        float em = __expf(-m);
        float Z  = Zl + (float)(SS - L) * em;
        wSw[lane]      = w0;
        wSw[64 + lane] = w1;
        float acc = 0.f;
#pragma unroll 16
        for (int t = 0; t < Lp; ++t)
            acc += wSw[t] * vh[((size_t)h * RMAX + t) * DD + lane];
        float invZ = 1.0f / Z;
        atomicAdd(&betap[h * DD + lane], acc * invZ);
        if (lane == 0) atomicAdd(&alphap[h], em * invZ);
    }
}

// -------- D3: out[e] = bo[e] + Wo[e,:].(beta + alpha o (bgA - vsumh)) / L ----
__global__ __launch_bounds__(256) void d3_kernel(
    const float* __restrict__ Wo, const float* __restrict__ bo,
    const float* __restrict__ ws, float* __restrict__ out) {
    __shared__ float z[EE];
    int tid = threadIdx.x;
    int lane = tid & 63, wave = tid >> 6;
    int L = ((const int*)ws)[1];

    {
        int h = tid >> 4;
        float4 beta = ((const float4*)(ws + OFF_BETA))[tid];
        float  a    = (ws + OFF_ALPHA)[h];
        float4 g    = ((const float4*)(ws + OFF_BGA))[tid];
        float4 vs   = ((const float4*)(ws + OFF_VSUM))[tid];
        ((float4*)z)[tid] = make_float4(beta.x + a * (g.x - vs.x),
                                        beta.y + a * (g.y - vs.y),
                                        beta.z + a * (g.z - vs.z),
                                        beta.w + a * (g.w - vs.w));
    }
    __syncthreads();

    int e = blockIdx.x * 4 + wave;
    const float4* wr = (const float4*)(Wo + (size_t)e * EE);
    const float4* z4 = (const float4*)z;
    float p = 0.f;
#pragma unroll
    for (int it = 0; it < 4; ++it) {
        float4 w = wr[it * 64 + lane], zz = z4[it * 64 + lane];
        p += w.x * zz.x + w.y * zz.y + w.z * zz.z + w.w * zz.w;
    }
#pragma unroll
    for (int off = 32; off; off >>= 1) p += __shfl_xor(p, off);
    if (lane == 0) out[e] = bo[e] + p / (float)L;
}

extern "C" void kernel_launch(void* const* d_in, const int* in_sizes, int n_in,
                              void* d_out, int out_size, void* d_ws, size_t ws_size,
                              hipStream_t stream) {
    const float* x   = (const float*)d_in[0];
    const float* Wq  = (const float*)d_in[1];
    const float* bq  = (const float*)d_in[2];
    const float* Wk  = (const float*)d_in[3];
    const float* bk  = (const float*)d_in[4];
    const float* Wv  = (const float*)d_in[5];
    const float* bv  = (const float*)d_in[6];
    const float* Wo  = (const float*)d_in[7];
    const float* bo  = (const float*)d_in[8];
    const int*   seg = (const int*)d_in[9];
    const int*   pos = (const int*)d_in[10];
    float*       out = (float*)d_out;
    float*       ws  = (float*)d_ws;

    d0_kernel<<<NCOL + NTR, 256, 0, stream>>>(x, seg, pos, ws);
    d1_kernel<<<NRED + NPROJ, 256, 0, stream>>>(Wq, bq, Wk, bk, Wv, bv, ws);
    d2_kernel<<<NBG + NVS + NATT, 256, 0, stream>>>(Wv, bv, ws);
    d3_kernel<<<EE / 4, 256, 0, stream>>>(Wo, bo, ws, out);
}

// Round 20
// 65.965 us; speedup vs baseline: 11.5961x; 1.0740x over previous
//
#include <hip/hip_runtime.h>
#include <math.h>

#define SS 4096
#define EE 1024
#define HH 16
#define DD 64
#define RMAX 128
#define NCOL 128
#define NTR  8
#define NRED 8
#define NPROJ 1536 // 3 m * 256 e-tiles(4e) * 2 r-tiles; rt in HIGH bit (XCD pairing)
#define NBG 64
#define NVS 16
#define NATT 256

// ---------------------------------------------------------------------------
// ws float offsets. LESSONS: (r9/r10) no 4KB-strided ws reads; (r3) no BULK
// global atomics; (r5/r7) no software grid barriers; (r13) no shallow-flight
// staging; (r14/r16/r18 ledger) d1 proj ~40us across scalar-W / LDS-W / W-once
// variants; r19 XCD-pairing (W HBM halved) only -3.4us => NOT fetch-bound.
// (r20 theory) all blocks sweep xT k=0..1023 in LOCKSTEP -> ~190 blocks hit
// the same 256B line simultaneously; per-XCD L2 serializes per requester ->
// latency x20, VALUBusy 18% despite 48% occupancy. Fix: per-block k-phase
// stagger (quadrant rotate + intra-quadrant offset, modular wrap).
//   meta   int[0..1]      (s0, L)
//   sumx   [EE]           @64
//   bgA    [EE]           @1088
//   betap  [HH][DD]       @2112   (atomic; zeroed by D1 block 0)
//   alphap [HH]           @3136
//   vsumh  [HH][DD]       @3200
//   partT  [EE][NCOL]     @8192
//   xT     [EE][RMAX]     @139264 (zero-padded rows r>=L)
//   qh     [HH][RMAX][DD] @270336 (rows L..Lp-1 zeroed)
//   kTh    [HH][DD][RMAX] @401408 (cols L..Lp-1 zeroed)
//   vh     [HH][RMAX][DD] @532480 (rows L..Lp-1 zeroed)
// ---------------------------------------------------------------------------
#define OFF_SUMX  64
#define OFF_BGA   1088
#define OFF_BETA  2112
#define OFF_ALPHA 3136
#define OFF_VSUM  3200
#define OFF_PART  8192
#define OFF_XT    (OFF_PART + EE * NCOL)
#define OFF_QH    (OFF_XT + EE * RMAX)
#define OFF_KTH   (OFF_QH + HH * RMAX * DD)
#define OFF_VH    (OFF_KTH + HH * DD * RMAX)

__device__ __forceinline__ void seg_scan(const int* __restrict__ seg,
                                         const int* __restrict__ posp,
                                         int* sh, int& s0, int& L) {
    if (threadIdx.x == 0) { sh[0] = SS; sh[1] = -1; }
    __syncthreads();
    int sid = seg[posp[0]];
    int lmin = SS, lmax = -1;
    for (int i = threadIdx.x; i < SS; i += 256)
        if (seg[i] == sid) { lmin = min(lmin, i); lmax = max(lmax, i); }
#pragma unroll
    for (int off = 32; off; off >>= 1) {
        lmin = min(lmin, __shfl_xor(lmin, off));
        lmax = max(lmax, __shfl_xor(lmax, off));
    }
    if ((threadIdx.x & 63) == 0) { atomicMin(&sh[0], lmin); atomicMax(&sh[1], lmax); }
    __syncthreads();
    s0 = sh[0];
    L  = sh[1] - sh[0] + 1;
    if (L > RMAX) L = RMAX;
    if (L < 1)    L = 1;
}

// -------- D0: colsum -> partT (128 blk) || x-seg transpose -> xT (8 blk) ----
__global__ __launch_bounds__(256) void d0_kernel(
    const float* __restrict__ x, const int* __restrict__ seg,
    const int* __restrict__ posp, float* __restrict__ ws) {
    int bid = blockIdx.x, tid = threadIdx.x;
    if (bid < NCOL) {
        float* partT = ws + OFF_PART;
        int r0 = bid * (SS / NCOL);
        const float4* x4 = (const float4*)x;
        float4 a = make_float4(0.f, 0.f, 0.f, 0.f);
#pragma unroll 8
        for (int r = 0; r < SS / NCOL; ++r) {
            float4 v = x4[(size_t)(r0 + r) * 256 + tid];
            a.x += v.x; a.y += v.y; a.z += v.z; a.w += v.w;
        }
        partT[(size_t)(4 * tid + 0) * NCOL + bid] = a.x;
        partT[(size_t)(4 * tid + 1) * NCOL + bid] = a.y;
        partT[(size_t)(4 * tid + 2) * NCOL + bid] = a.z;
        partT[(size_t)(4 * tid + 3) * NCOL + bid] = a.w;
        return;
    }
    __shared__ float t[128 * 129];
    __shared__ int sh[2];
    int s0, L;
    seg_scan(seg, posp, sh, s0, L);
    int kb = bid - NCOL;
    if (kb == 0 && tid == 0) { ((int*)ws)[0] = s0; ((int*)ws)[1] = L; }
    int k0 = kb * 128;
    float* xT = ws + OFF_XT;
    for (int idx = tid; idx < 128 * 32; idx += 256) {
        int r = idx >> 5, c4 = idx & 31;
        float4 v = make_float4(0.f, 0.f, 0.f, 0.f);
        if (r < L) v = *(const float4*)(x + (size_t)(s0 + r) * EE + k0 + c4 * 4);
        t[r * 129 + c4 * 4 + 0] = v.x;
        t[r * 129 + c4 * 4 + 1] = v.y;
        t[r * 129 + c4 * 4 + 2] = v.z;
        t[r * 129 + c4 * 4 + 3] = v.w;
    }
    __syncthreads();
    for (int idx = tid; idx < 128 * 32; idx += 256) {
        int k = idx >> 5, r4 = idx & 31;
        float4 o;
        o.x = t[(r4 * 4 + 0) * 129 + k];
        o.y = t[(r4 * 4 + 1) * 129 + k];
        o.z = t[(r4 * 4 + 2) * 129 + k];
        o.w = t[(r4 * 4 + 3) * 129 + k];
        *(float4*)(xT + (size_t)(k0 + k) * RMAX + r4 * 4) = o;
    }
}

// -------- D1: sumx reduce + zero accum (8 blk) || QKV projection (1536 blk) --
// r12 structure + rt-high-bit XCD pairing + k-phase stagger (r20).
__global__ __launch_bounds__(256) void d1_kernel(
    const float* __restrict__ Wq, const float* __restrict__ bq,
    const float* __restrict__ Wk, const float* __restrict__ bk,
    const float* __restrict__ Wv, const float* __restrict__ bv,
    float* __restrict__ ws) {
    int bid = blockIdx.x, tid = threadIdx.x;
    if (bid < NRED) {
        if (bid == 0) {   // zero betap+alphap atomic accumulators
            for (int i = tid; i < 1088; i += 256) (ws + OFF_BETA)[i] = 0.f;
        }
        const float* partT = ws + OFF_PART;
        int e  = bid * 128 + (tid >> 1);
        int c0 = (tid & 1) * 64;
        const float4* p4 = (const float4*)(partT + (size_t)e * NCOL + c0);
        float4 s4 = make_float4(0.f, 0.f, 0.f, 0.f);
#pragma unroll
        for (int i = 0; i < 16; ++i) {
            float4 v = p4[i];
            s4.x += v.x; s4.y += v.y; s4.z += v.z; s4.w += v.w;
        }
        float s = s4.x + s4.y + s4.z + s4.w;
        s += __shfl_xor(s, 1);
        if ((tid & 1) == 0) (ws + OFF_SUMX)[e] = s;
        return;
    }
    __shared__ float red[16 * 66];
    int L  = ((const int*)ws)[1];
    int Lp = (L + 63) & ~63;
    int pid = bid - NRED;         // 0..1535
    // rt in HIGH position: blocks p and p+768 share a W slice AND an XCD
    // (768 % 8 == 0 -> same blockIdx%8 -> same XCD; second fetch L2-hits).
    int rt  = (pid >= 768) ? 1 : 0;
    int rem = pid - rt * 768;     // 0..767
    int m   = rem >> 8;           // 0..2
    int eb  = rem & 255;          // 0..255 (4 e each)
    int r0  = rt * 64;
    if (r0 >= Lp) return;
    int e0 = eb * 4;
    const float* W = (m == 0) ? Wq : ((m == 1) ? Wk : Wv);
    const float* b = (m == 0) ? bq : ((m == 1) ? bk : bv);
    int lane = tid & 63;
    int w4 = __builtin_amdgcn_readfirstlane(tid >> 6);   // wave id, uniform
    const float* xcol = ws + OFF_XT + r0 + lane;
    // k-phase stagger: quadrant rotated by block, intra-quadrant offset by
    // block, modular wrap. Pairs (p, p+768) share identical phase (768%4==0,
    // (768>>2)%32==0) so the r19 W-sharing is preserved.
    int kq = ((w4 + pid) & 3) * 256;          // this wave's k quadrant
    int ko = ((pid >> 2) & 31) * 8;           // intra-quadrant start, 8-aligned
    const float* wr0 = W + (size_t)e0 * EE + kq;         // uniform
    float acc0 = 0.f, acc1 = 0.f, acc2 = 0.f, acc3 = 0.f;
    float xv0[8], xv1[8];
#pragma unroll
    for (int u = 0; u < 8; ++u) xv0[u] = xcol[(size_t)(kq + ko + u) * RMAX];
    for (int kk = 0; kk < 256; kk += 16) {
        int kA = (ko + kk) & 255;
        int kB = (ko + kk + 8) & 255;
        int kC = (ko + kk + 16) & 255;        // wraps to ko on last iter (harmless)
        // prefetch second half while first computes
#pragma unroll
        for (int u = 0; u < 8; ++u)
            xv1[u] = xcol[(size_t)(kq + kB + u) * RMAX];
#pragma unroll
        for (int u = 0; u < 8; ++u) {
            float w0 = wr0[0 * EE + kA + u];
            float w1 = wr0[1 * EE + kA + u];
            float w2 = wr0[2 * EE + kA + u];
            float w3 = wr0[3 * EE + kA + u];
            acc0 += xv0[u] * w0; acc1 += xv0[u] * w1;
            acc2 += xv0[u] * w2; acc3 += xv0[u] * w3;
        }
        // prefetch next iteration's first half
#pragma unroll
        for (int u = 0; u < 8; ++u)
            xv0[u] = xcol[(size_t)(kq + kC + u) * RMAX];
#pragma unroll
        for (int u = 0; u < 8; ++u) {
            float w0 = wr0[0 * EE + kB + u];
            float w1 = wr0[1 * EE + kB + u];
            float w2 = wr0[2 * EE + kB + u];
            float w3 = wr0[3 * EE + kB + u];
            acc0 += xv1[u] * w0; acc1 += xv1[u] * w1;
            acc2 += xv1[u] * w2; acc3 += xv1[u] * w3;
        }
    }
    red[(w4 * 4 + 0) * 66 + lane] = acc0;
    red[(w4 * 4 + 1) * 66 + lane] = acc1;
    red[(w4 * 4 + 2) * 66 + lane] = acc2;
    red[(w4 * 4 + 3) * 66 + lane] = acc3;
    __syncthreads();
    int p  = tid >> 6;            // wave -> e index (4 each)
    int rg = r0 + lane;
    float* qh  = ws + OFF_QH;
    float* kTh = ws + OFF_KTH;
    float* vh  = ws + OFF_VH;
    int h = e0 >> 6, d0 = (e0 & 63) + p;
    float v = 0.f;
    if (rg < L)
        v = red[(0 * 4 + p) * 66 + lane] + red[(1 * 4 + p) * 66 + lane]
          + red[(2 * 4 + p) * 66 + lane] + red[(3 * 4 + p) * 66 + lane]
          + b[e0 + p];
    if (m == 1) kTh[(size_t)(h * DD + d0) * RMAX + rg] = v;
    else        ((m == 0) ? qh : vh)[((size_t)h * RMAX + rg) * DD + d0] = v;
}

// -------- D2: bgA (64) || vsumh (16) || attention, 1 wave per (r,h) (256) ----
__global__ __launch_bounds__(256) void d2_kernel(
    const float* __restrict__ Wv, const float* __restrict__ bv,
    float* __restrict__ ws) {
    __shared__ float qS[4 * 64];
    __shared__ float wS[4 * 128];
    __shared__ float vp_[4][64];
    const float* sumx = ws + OFF_SUMX;
    float* bgA    = ws + OFF_BGA;
    float* betap  = ws + OFF_BETA;
    float* alphap = ws + OFF_ALPHA;
    float* vsumh  = ws + OFF_VSUM;
    const float* qh  = ws + OFF_QH;
    const float* kTh = ws + OFF_KTH;
    const float* vh  = ws + OFF_VH;

    int bid = blockIdx.x, tid = threadIdx.x;
    int lane = tid & 63, wave = tid >> 6;
    int L  = ((const int*)ws)[1];
    int Lp = (L + 63) & ~63;

    if (bid < NBG) {
        int e = bid * 16 + (tid >> 4);
        int j = tid & 15;
        const float4* wr  = (const float4*)(Wv + (size_t)e * EE);
        const float4* sx4 = (const float4*)sumx;
        float p = 0.f;
#pragma unroll
        for (int jj = 0; jj < 16; ++jj) {
            float4 w = wr[jj * 16 + j], z = sx4[jj * 16 + j];
            p += w.x * z.x + w.y * z.y + w.z * z.z + w.w * z.w;
        }
        p += __shfl_xor(p, 8);
        p += __shfl_xor(p, 4);
        p += __shfl_xor(p, 2);
        p += __shfl_xor(p, 1);
        if (j == 0) bgA[e] = p + (float)SS * bv[e];
        return;
    }
    if (bid < NBG + NVS) {
        int h = bid - NBG;
        float s = 0.f;
        for (int t = wave; t < Lp; t += 4)
            s += vh[((size_t)h * RMAX + t) * DD + lane];
        vp_[wave][lane] = s;
        __syncthreads();
        if (wave == 0)
            vsumh[h * DD + lane] = vp_[0][lane] + vp_[1][lane]
                                 + vp_[2][lane] + vp_[3][lane];
        return;
    }

    int aid = bid - NBG - NVS;
    int gidbase = aid * 4 + wave;
    int pairs = L * HH;
    float* qSw = qS + wave * 64;
    float* wSw = wS + wave * 128;
    for (int wg = gidbase; wg < pairs; wg += NATT * 4) {
        int h = wg & (HH - 1);
        int r = wg >> 4;
        qSw[lane] = qh[((size_t)h * RMAX + r) * DD + lane];
        float s0 = 0.f, s1 = 0.f;
#pragma unroll
        for (int d = 0; d < 64; ++d) {
            float qd = qSw[d];
            const float* kr = kTh + (size_t)(h * DD + d) * RMAX;
            s0 += qd * kr[lane];
            s1 += qd * kr[64 + lane];
        }
        float v0 = (lane < L)      ? s0 : -3.0e38f;
        float v1 = (64 + lane < L) ? s1 : -3.0e38f;
        float m = fmaxf(0.f, fmaxf(v0, v1));
#pragma unroll
        for (int off = 32; off; off >>= 1) m = fmaxf(m, __shfl_xor(m, off));
        float w0 = (lane < L)      ? __expf(s0 - m) : 0.f;
        float w1 = (64 + lane < L) ? __expf(s1 - m) : 0.f;
        float Zl = w0 + w1;
#pragma unroll
        for (int off = 32; off; off >>= 1) Zl += __shfl_xor(Zl, off);
        float em = __expf(-m);
        float Z  = Zl + (float)(SS - L) * em;
        wSw[lane]      = w0;
        wSw[64 + lane] = w1;
        float acc = 0.f;
#pragma unroll 16
        for (int t = 0; t < Lp; ++t)
            acc += wSw[t] * vh[((size_t)h * RMAX + t) * DD + lane];
        float invZ = 1.0f / Z;
        atomicAdd(&betap[h * DD + lane], acc * invZ);
        if (lane == 0) atomicAdd(&alphap[h], em * invZ);
    }
}

// -------- D3: out[e] = bo[e] + Wo[e,:].(beta + alpha o (bgA - vsumh)) / L ----
__global__ __launch_bounds__(256) void d3_kernel(
    const float* __restrict__ Wo, const float* __restrict__ bo,
    const float* __restrict__ ws, float* __restrict__ out) {
    __shared__ float z[EE];
    int tid = threadIdx.x;
    int lane = tid & 63, wave = tid >> 6;
    int L = ((const int*)ws)[1];

    {
        int h = tid >> 4;
        float4 beta = ((const float4*)(ws + OFF_BETA))[tid];
        float  a    = (ws + OFF_ALPHA)[h];
        float4 g    = ((const float4*)(ws + OFF_BGA))[tid];
        float4 vs   = ((const float4*)(ws + OFF_VSUM))[tid];
        ((float4*)z)[tid] = make_float4(beta.x + a * (g.x - vs.x),
                                        beta.y + a * (g.y - vs.y),
                                        beta.z + a * (g.z - vs.z),
                                        beta.w + a * (g.w - vs.w));
    }
    __syncthreads();

    int e = blockIdx.x * 4 + wave;
    const float4* wr = (const float4*)(Wo + (size_t)e * EE);
    const float4* z4 = (const float4*)z;
    float p = 0.f;
#pragma unroll
    for (int it = 0; it < 4; ++it) {
        float4 w = wr[it * 64 + lane], zz = z4[it * 64 + lane];
        p += w.x * zz.x + w.y * zz.y + w.z * zz.z + w.w * zz.w;
    }
#pragma unroll
    for (int off = 32; off; off >>= 1) p += __shfl_xor(p, off);
    if (lane == 0) out[e] = bo[e] + p / (float)L;
}

extern "C" void kernel_launch(void* const* d_in, const int* in_sizes, int n_in,
                              void* d_out, int out_size, void* d_ws, size_t ws_size,
                              hipStream_t stream) {
    const float* x   = (const float*)d_in[0];
    const float* Wq  = (const float*)d_in[1];
    const float* bq  = (const float*)d_in[2];
    const float* Wk  = (const float*)d_in[3];
    const float* bk  = (const float*)d_in[4];
    const float* Wv  = (const float*)d_in[5];
    const float* bv  = (const float*)d_in[6];
    const float* Wo  = (const float*)d_in[7];
    const float* bo  = (const float*)d_in[8];
    const int*   seg = (const int*)d_in[9];
    const int*   pos = (const int*)d_in[10];
    float*       out = (float*)d_out;
    float*       ws  = (float*)d_ws;

    d0_kernel<<<NCOL + NTR, 256, 0, stream>>>(x, seg, pos, ws);
    d1_kernel<<<NRED + NPROJ, 256, 0, stream>>>(Wq, bq, Wk, bk, Wv, bv, ws);
    d2_kernel<<<NBG + NVS + NATT, 256, 0, stream>>>(Wv, bv, ws);
    d3_kernel<<<EE / 4, 256, 0, stream>>>(Wo, bo, ws, out);
}